// Round 8
// baseline (499.658 us; speedup 1.0000x reference)
//
#include <hip/hip_runtime.h>
#include <hip/hip_fp16.h>

#define THREADS 256
#define HTHREADS 512
#define NB 256           // nodes per bucket
#define KMAX 400         // >= ceil(N/NB)=391
#define NCHUNK 1024      // edge chunks for bucket sort (4 blocks/CU)

struct alignas(8) Half4 { __half2 a, b; };

// ---------------------------------------------------------------------------
// detect -> hist(LDS bucket histogram) -> colscan -> basescan ->
// passB (packed bucket-sorted edges) -> passC (per-bucket counting sort ->
// node CSR + rowptr + dinv) -> gemm1 (reg-blocked 4x4, g1 fp16) ->
// agg1 (32-lane/node half2 register-gather) -> gemm2 (reg-blocked 4x4) ->
// agg2 (16-lane/node, out fp32)
//
// R7 lesson: 1 ds_read per FMA starves the VALU (gemm1 VALUBusy 20%).
// Register blocking: 2x ds_read_b128 per 16 FMAs.
// packed edge = (src << 8) | (dst & 255); bucket = dst >> 8
// ---------------------------------------------------------------------------

__global__ void k_detect(const int* __restrict__ e32, int* __restrict__ flag) {
    if (blockIdx.x == 0 && threadIdx.x == 0) {
        int st = 2;
        for (int i = 0; i < 64; ++i)
            if (e32[2 * i + 1] != 0) { st = 1; break; }
        *flag = st;
    }
}

__global__ __launch_bounds__(HTHREADS) void k_hist(const int* __restrict__ eidx,
                                                   const int* __restrict__ flag,
                                                   int E, int C, int K,
                                                   int* __restrict__ H) {
    __shared__ int hl[KMAX];
    int st = *flag;
    for (int i = threadIdx.x; i < K; i += HTHREADS) hl[i] = 0;
    __syncthreads();
    int s0 = blockIdx.x * C;
    int s1 = min(s0 + C, E);
    for (int e = s0 + threadIdx.x; e < s1; e += HTHREADS) {
        int d = eidx[(size_t)(E + e) * st];
        atomicAdd(&hl[d >> 8], 1);
    }
    __syncthreads();
    for (int i = threadIdx.x; i < K; i += HTHREADS)
        H[(size_t)blockIdx.x * K + i] = hl[i];
}

__global__ __launch_bounds__(THREADS) void k_colscan(int* __restrict__ H,
                                                     int* __restrict__ btot,
                                                     int K, int nchunk) {
    int t = blockIdx.x * THREADS + threadIdx.x;
    if (t >= K) return;
    int run = 0;
    for (int c = 0; c < nchunk; ++c) {
        int v = H[(size_t)c * K + t];
        H[(size_t)c * K + t] = run;
        run += v;
    }
    btot[t] = run;
}

// exclusive scan of K<=2048 bucket totals, single block
__global__ __launch_bounds__(1024) void k_basescan(const int* __restrict__ btot,
                                                   int* __restrict__ base, int K) {
    __shared__ int s0[2048], s1[2048];
    int t = threadIdx.x;
    for (int i = t; i < 2048; i += 1024) s0[i] = (i < K) ? btot[i] : 0;
    __syncthreads();
    int* src = s0; int* dst = s1;
    for (int off = 1; off < 2048; off <<= 1) {
        for (int i = t; i < 2048; i += 1024)
            dst[i] = src[i] + (i >= off ? src[i - off] : 0);
        __syncthreads();
        int* tmp = src; src = dst; dst = tmp;
    }
    for (int i = t; i < 2048; i += 1024)
        if (i < K) base[i] = (i == 0) ? 0 : src[i - 1];
    if (t == 0) base[K] = src[K - 1];
}

__global__ __launch_bounds__(HTHREADS) void k_passB(const int* __restrict__ eidx,
                                                    const int* __restrict__ flag,
                                                    int E, int C, int K,
                                                    const int* __restrict__ H,
                                                    const int* __restrict__ base,
                                                    unsigned int* __restrict__ packed) {
    __shared__ int cur[KMAX];
    int st = *flag;
    for (int i = threadIdx.x; i < K; i += HTHREADS)
        cur[i] = base[i] + H[(size_t)blockIdx.x * K + i];
    __syncthreads();
    int s0 = blockIdx.x * C;
    int s1 = min(s0 + C, E);
    for (int e = s0 + threadIdx.x; e < s1; e += HTHREADS) {
        int s = eidx[(size_t)e * st];
        int d = eidx[(size_t)(E + e) * st];
        int pos = atomicAdd(&cur[d >> 8], 1);
        packed[pos] = ((unsigned)s << 8) | (unsigned)(d & 255);
    }
}

// per-bucket counting sort: packed -> csr (src by node), rowptr, dinv
__global__ __launch_bounds__(NB) void k_passC(const unsigned int* __restrict__ pk,
                                              const int* __restrict__ base,
                                              int K, int N,
                                              int* __restrict__ csr,
                                              int* __restrict__ rowptr,
                                              float* __restrict__ dinv) {
    __shared__ int cnt[NB];
    __shared__ int scn[NB];
    __shared__ int cur[NB];
    int b = blockIdx.x;
    int b0 = base[b], b1e = base[b + 1];
    int t = threadIdx.x;
    cnt[t] = 0;
    __syncthreads();
    for (int e = b0 + t; e < b1e; e += NB)
        atomicAdd(&cnt[pk[e] & 255u], 1);
    __syncthreads();
    int val = cnt[t];
    scn[t] = val;
    __syncthreads();
    for (int off = 1; off < NB; off <<= 1) {
        int tmp = (t >= off) ? scn[t - off] : 0;
        __syncthreads();
        scn[t] += tmp;
        __syncthreads();
    }
    int excl = b0 + scn[t] - val;
    cur[t] = excl;
    int v = b * NB + t;
    if (v < N) {
        rowptr[v] = excl;
        dinv[v] = rsqrtf((float)val + 1.0f);
    }
    if (b == K - 1 && t == 0) rowptr[N] = b1e;
    __syncthreads();
    for (int e = b0 + t; e < b1e; e += NB) {
        unsigned p = pk[e];
        int pos = atomicAdd(&cur[p & 255u], 1);
        csr[pos] = (int)(p >> 8);
    }
}

// reg-blocked GEMM1: 64-row tile, 4x4 per thread, xT transposed in LDS.
// g1[r,c] = half((x[r,:] @ W1[:,c]) * dinv[r])
__global__ __launch_bounds__(THREADS) void k_gemm1(const float* __restrict__ x,
                                                   const float* __restrict__ W1,
                                                   const float* __restrict__ dinv,
                                                   __half* __restrict__ g1, int N) {
    __shared__ float xT[128 * 65];   // [k][r], stride 65 -> bank (k+r)%32
    __shared__ float Wl[128 * 64];   // [k][c]
    for (int i = threadIdx.x; i < 128 * 64; i += THREADS) Wl[i] = W1[i];
    int row0 = blockIdx.x * 64;
    int kq = threadIdx.x & 31;   // float4 index along k
    int rr = threadIdx.x >> 5;   // 0..7
#pragma unroll
    for (int it = 0; it < 8; ++it) {
        int r = rr + it * 8;
        int gr = row0 + r;
        float4 xv = make_float4(0.f, 0.f, 0.f, 0.f);
        if (gr < N) xv = *(const float4*)(x + (size_t)gr * 128 + kq * 4);
        xT[(4 * kq + 0) * 65 + r] = xv.x;
        xT[(4 * kq + 1) * 65 + r] = xv.y;
        xT[(4 * kq + 2) * 65 + r] = xv.z;
        xT[(4 * kq + 3) * 65 + r] = xv.w;
    }
    __syncthreads();
    int tx = threadIdx.x & 15;   // col block: c = tx*4
    int ty = threadIdx.x >> 4;   // row block: r = ty*4
    float acc[4][4] = {};
#pragma unroll 4
    for (int k = 0; k < 128; ++k) {
        float4 a = *(const float4*)&xT[k * 65 + ty * 4];
        float4 b = *(const float4*)&Wl[k * 64 + tx * 4];
        acc[0][0] = fmaf(a.x, b.x, acc[0][0]);
        acc[0][1] = fmaf(a.x, b.y, acc[0][1]);
        acc[0][2] = fmaf(a.x, b.z, acc[0][2]);
        acc[0][3] = fmaf(a.x, b.w, acc[0][3]);
        acc[1][0] = fmaf(a.y, b.x, acc[1][0]);
        acc[1][1] = fmaf(a.y, b.y, acc[1][1]);
        acc[1][2] = fmaf(a.y, b.z, acc[1][2]);
        acc[1][3] = fmaf(a.y, b.w, acc[1][3]);
        acc[2][0] = fmaf(a.z, b.x, acc[2][0]);
        acc[2][1] = fmaf(a.z, b.y, acc[2][1]);
        acc[2][2] = fmaf(a.z, b.z, acc[2][2]);
        acc[2][3] = fmaf(a.z, b.w, acc[2][3]);
        acc[3][0] = fmaf(a.w, b.x, acc[3][0]);
        acc[3][1] = fmaf(a.w, b.y, acc[3][1]);
        acc[3][2] = fmaf(a.w, b.z, acc[3][2]);
        acc[3][3] = fmaf(a.w, b.w, acc[3][3]);
    }
#pragma unroll
    for (int i = 0; i < 4; ++i) {
        int gr = row0 + ty * 4 + i;
        if (gr < N) {
            float dr = dinv[gr];
            Half4 o;
            o.a = __floats2half2_rn(acc[i][0] * dr, acc[i][1] * dr);
            o.b = __floats2half2_rn(acc[i][2] * dr, acc[i][3] * dr);
            *(Half4*)(g1 + (size_t)gr * 64 + tx * 4) = o;
        }
    }
}

// 32 lanes per node, lane f handles half2 feature pair f; 8-deep gather
__global__ __launch_bounds__(THREADS) void k_agg1(const int* __restrict__ rowptr,
                                                  const int* __restrict__ csr,
                                                  const __half* __restrict__ g1h,
                                                  const float* __restrict__ dinv,
                                                  const float* __restrict__ b1,
                                                  __half* __restrict__ h1h, int N) {
    const __half2* g1 = (const __half2*)g1h;
    __half2* h1 = (__half2*)h1h;
    int v = (blockIdx.x * THREADS + threadIdx.x) >> 5;
    if (v >= N) return;
    int f = threadIdx.x & 31;
    int beg = rowptr[v], end = rowptr[v + 1];
    float2 s = __half22float2(g1[(size_t)v * 32 + f]);
    float sx = s.x, sy = s.y;
    int j = beg;
    for (; j + 8 <= end; j += 8) {
        int s0 = csr[j + 0], s1 = csr[j + 1], s2 = csr[j + 2], s3 = csr[j + 3];
        int s4 = csr[j + 4], s5 = csr[j + 5], s6 = csr[j + 6], s7 = csr[j + 7];
        __half2 a0 = g1[(size_t)s0 * 32 + f];
        __half2 a1 = g1[(size_t)s1 * 32 + f];
        __half2 a2 = g1[(size_t)s2 * 32 + f];
        __half2 a3 = g1[(size_t)s3 * 32 + f];
        __half2 a4 = g1[(size_t)s4 * 32 + f];
        __half2 a5 = g1[(size_t)s5 * 32 + f];
        __half2 a6 = g1[(size_t)s6 * 32 + f];
        __half2 a7 = g1[(size_t)s7 * 32 + f];
        float2 f0 = __half22float2(a0), f1 = __half22float2(a1);
        float2 f2 = __half22float2(a2), f3 = __half22float2(a3);
        float2 f4 = __half22float2(a4), f5 = __half22float2(a5);
        float2 f6 = __half22float2(a6), f7 = __half22float2(a7);
        sx += ((f0.x + f1.x) + (f2.x + f3.x)) + ((f4.x + f5.x) + (f6.x + f7.x));
        sy += ((f0.y + f1.y) + (f2.y + f3.y)) + ((f4.y + f5.y) + (f6.y + f7.y));
    }
    for (; j < end; ++j) {
        float2 a = __half22float2(g1[(size_t)csr[j] * 32 + f]);
        sx += a.x; sy += a.y;
    }
    float dr = dinv[v];
    float h0 = fmaxf(fmaf(dr, sx, b1[2 * f + 0]), 0.0f);
    float h1v = fmaxf(fmaf(dr, sy, b1[2 * f + 1]), 0.0f);
    h1[(size_t)v * 32 + f] = __floats2half2_rn(h0, h1v);
}

// reg-blocked GEMM2: 128-row tile, 4x4 per thread, h1T (fp32) in LDS.
// g2[r,c] = half((h1[r,:] @ W2[:,c]) * dinv[r])
__global__ __launch_bounds__(THREADS) void k_gemm2(const __half* __restrict__ h1,
                                                   const float* __restrict__ W2,
                                                   const float* __restrict__ dinv,
                                                   __half* __restrict__ g2, int N) {
    __shared__ float hT[64 * 129];   // [k][r], stride 129 -> bank (k+r)%32
    __shared__ float Wl[64 * 32];    // [k][c]
    for (int i = threadIdx.x; i < 64 * 32; i += THREADS) Wl[i] = W2[i];
    int row0 = blockIdx.x * 128;
    int kq = threadIdx.x & 31;   // half2 index along k
    int rr = threadIdx.x >> 5;   // 0..7
#pragma unroll
    for (int it = 0; it < 16; ++it) {
        int r = rr + it * 8;
        int gr = row0 + r;
        __half2 v = __floats2half2_rn(0.f, 0.f);
        if (gr < N) v = ((const __half2*)(h1 + (size_t)gr * 64))[kq];
        float2 fv = __half22float2(v);
        hT[(2 * kq + 0) * 129 + r] = fv.x;
        hT[(2 * kq + 1) * 129 + r] = fv.y;
    }
    __syncthreads();
    int tx = threadIdx.x & 7;    // col block: c = tx*4
    int ty = threadIdx.x >> 3;   // row block: r = ty*4 (0..124)
    float acc[4][4] = {};
#pragma unroll 4
    for (int k = 0; k < 64; ++k) {
        float4 a = *(const float4*)&hT[k * 129 + ty * 4];
        float4 b = *(const float4*)&Wl[k * 32 + tx * 4];
        acc[0][0] = fmaf(a.x, b.x, acc[0][0]);
        acc[0][1] = fmaf(a.x, b.y, acc[0][1]);
        acc[0][2] = fmaf(a.x, b.z, acc[0][2]);
        acc[0][3] = fmaf(a.x, b.w, acc[0][3]);
        acc[1][0] = fmaf(a.y, b.x, acc[1][0]);
        acc[1][1] = fmaf(a.y, b.y, acc[1][1]);
        acc[1][2] = fmaf(a.y, b.z, acc[1][2]);
        acc[1][3] = fmaf(a.y, b.w, acc[1][3]);
        acc[2][0] = fmaf(a.z, b.x, acc[2][0]);
        acc[2][1] = fmaf(a.z, b.y, acc[2][1]);
        acc[2][2] = fmaf(a.z, b.z, acc[2][2]);
        acc[2][3] = fmaf(a.z, b.w, acc[2][3]);
        acc[3][0] = fmaf(a.w, b.x, acc[3][0]);
        acc[3][1] = fmaf(a.w, b.y, acc[3][1]);
        acc[3][2] = fmaf(a.w, b.z, acc[3][2]);
        acc[3][3] = fmaf(a.w, b.w, acc[3][3]);
    }
#pragma unroll
    for (int i = 0; i < 4; ++i) {
        int gr = row0 + ty * 4 + i;
        if (gr < N) {
            float dr = dinv[gr];
            Half4 o;
            o.a = __floats2half2_rn(acc[i][0] * dr, acc[i][1] * dr);
            o.b = __floats2half2_rn(acc[i][2] * dr, acc[i][3] * dr);
            *(Half4*)(g2 + (size_t)gr * 32 + tx * 4) = o;
        }
    }
}

// 16 lanes per node, lane f handles half2 feature pair f; 8-deep gather
__global__ __launch_bounds__(THREADS) void k_agg2(const int* __restrict__ rowptr,
                                                  const int* __restrict__ csr,
                                                  const __half* __restrict__ g2h,
                                                  const float* __restrict__ dinv,
                                                  const float* __restrict__ b2,
                                                  float* __restrict__ out, int N) {
    const __half2* g2 = (const __half2*)g2h;
    int v = (blockIdx.x * THREADS + threadIdx.x) >> 4;
    if (v >= N) return;
    int f = threadIdx.x & 15;
    int beg = rowptr[v], end = rowptr[v + 1];
    float2 s = __half22float2(g2[(size_t)v * 16 + f]);
    float sx = s.x, sy = s.y;
    int j = beg;
    for (; j + 8 <= end; j += 8) {
        int s0 = csr[j + 0], s1 = csr[j + 1], s2 = csr[j + 2], s3 = csr[j + 3];
        int s4 = csr[j + 4], s5 = csr[j + 5], s6 = csr[j + 6], s7 = csr[j + 7];
        __half2 a0 = g2[(size_t)s0 * 16 + f];
        __half2 a1 = g2[(size_t)s1 * 16 + f];
        __half2 a2 = g2[(size_t)s2 * 16 + f];
        __half2 a3 = g2[(size_t)s3 * 16 + f];
        __half2 a4 = g2[(size_t)s4 * 16 + f];
        __half2 a5 = g2[(size_t)s5 * 16 + f];
        __half2 a6 = g2[(size_t)s6 * 16 + f];
        __half2 a7 = g2[(size_t)s7 * 16 + f];
        float2 f0 = __half22float2(a0), f1 = __half22float2(a1);
        float2 f2 = __half22float2(a2), f3 = __half22float2(a3);
        float2 f4 = __half22float2(a4), f5 = __half22float2(a5);
        float2 f6 = __half22float2(a6), f7 = __half22float2(a7);
        sx += ((f0.x + f1.x) + (f2.x + f3.x)) + ((f4.x + f5.x) + (f6.x + f7.x));
        sy += ((f0.y + f1.y) + (f2.y + f3.y)) + ((f4.y + f5.y) + (f6.y + f7.y));
    }
    for (; j < end; ++j) {
        float2 a = __half22float2(g2[(size_t)csr[j] * 16 + f]);
        sx += a.x; sy += a.y;
    }
    float dr = dinv[v];
    float2 o;
    o.x = fmaf(dr, sx, b2[2 * f + 0]);
    o.y = fmaf(dr, sy, b2[2 * f + 1]);
    ((float2*)out)[(size_t)v * 16 + f] = o;
}

extern "C" void kernel_launch(void* const* d_in, const int* in_sizes, int n_in,
                              void* d_out, int out_size, void* d_ws, size_t ws_size,
                              hipStream_t stream) {
    const float* x  = (const float*)d_in[0];
    const int* eidx = (const int*)d_in[1];
    const float* W1 = (const float*)d_in[2];
    const float* b1 = (const float*)d_in[3];
    const float* W2 = (const float*)d_in[4];
    const float* b2 = (const float*)d_in[5];
    float* out = (float*)d_out;

    const int N = in_sizes[0] / 128;   // 100000
    const int E = in_sizes[1] / 2;     // 3200000
    const int K = (N + NB - 1) / NB;   // 391
    const int C = (E + NCHUNK - 1) / NCHUNK;

    // ws layout (ints), no aliasing; total ~61 MB
    int* flag   = (int*)d_ws;                            // 64
    int* H      = flag + 64;                             // NCHUNK*400
    int* btot   = H + (size_t)NCHUNK * 400;              // 400
    int* base   = btot + 400;                            // 448
    unsigned int* packed = (unsigned int*)(base + 448);  // E
    int* csr    = (int*)(packed + E);                    // E
    int* rowptr = csr + E;                               // N+1 (100032)
    float* dinv = (float*)(rowptr + 100032);             // 100032
    __half* g1  = (__half*)(dinv + 100032);              // N*64 halfs
    __half* h1  = g1 + (size_t)N * 64;                   // N*64 halfs
    __half* g2  = h1 + (size_t)N * 64;                   // N*32 halfs

    int nblkK = (K + THREADS - 1) / THREADS;

    k_detect<<<1, 64, 0, stream>>>(eidx, flag);
    k_hist<<<NCHUNK, HTHREADS, 0, stream>>>(eidx, flag, E, C, K, H);
    k_colscan<<<nblkK, THREADS, 0, stream>>>(H, btot, K, NCHUNK);
    k_basescan<<<1, 1024, 0, stream>>>(btot, base, K);
    k_passB<<<NCHUNK, HTHREADS, 0, stream>>>(eidx, flag, E, C, K, H, base, packed);
    k_passC<<<K, NB, 0, stream>>>(packed, base, K, N, csr, rowptr, dinv);
    k_gemm1<<<(N + 63) / 64, THREADS, 0, stream>>>(x, W1, dinv, g1, N);
    k_agg1<<<(N * 32 + THREADS - 1) / THREADS, THREADS, 0, stream>>>(rowptr, csr, g1, dinv, b1, h1, N);
    k_gemm2<<<(N + 127) / 128, THREADS, 0, stream>>>(h1, W2, dinv, g2, N);
    k_agg2<<<(N * 16 + THREADS - 1) / THREADS, THREADS, 0, stream>>>(rowptr, csr, g2, dinv, b2, out, N);
}

// Round 9
// 276.443 us; speedup vs baseline: 1.8075x; 1.8075x over previous
//
#include <hip/hip_runtime.h>
#include <hip/hip_fp16.h>

#define THREADS 256
#define HTHREADS 512
#define NB 256           // nodes per bucket
#define KMAX 400         // >= ceil(N/NB)=391
#define NCHUNK 1024      // edge chunks for bucket sort (4 blocks/CU)

struct alignas(8) Half4 { __half2 a, b; };

// ---------------------------------------------------------------------------
// detect -> hist(LDS bucket histogram) -> colscan (WAVE per bucket, shfl scan)
// -> basescan -> passB (packed bucket-sorted edges) -> passC (per-bucket
// counting sort -> node CSR + rowptr + dinv) -> gemm1 (reg-blocked 4x4) ->
// agg1 (32-lane/node half2 gather) -> gemm2 (reg-blocked 4x4) ->
// agg2 (16-lane/node, out fp32)
//
// R8 lesson: scaling NCHUNK 256->1024 made the serial-per-thread colscan the
// bottleneck (241 us at 0.08% occupancy). Scan work must parallelize with
// NCHUNK: wave per bucket, 64 chunks per shfl-scan iteration.
// packed edge = (src << 8) | (dst & 255); bucket = dst >> 8
// ---------------------------------------------------------------------------

__global__ void k_detect(const int* __restrict__ e32, int* __restrict__ flag) {
    if (blockIdx.x == 0 && threadIdx.x == 0) {
        int st = 2;
        for (int i = 0; i < 64; ++i)
            if (e32[2 * i + 1] != 0) { st = 1; break; }
        *flag = st;
    }
}

__global__ __launch_bounds__(HTHREADS) void k_hist(const int* __restrict__ eidx,
                                                   const int* __restrict__ flag,
                                                   int E, int C, int K,
                                                   int* __restrict__ H) {
    __shared__ int hl[KMAX];
    int st = *flag;
    for (int i = threadIdx.x; i < K; i += HTHREADS) hl[i] = 0;
    __syncthreads();
    int s0 = blockIdx.x * C;
    int s1 = min(s0 + C, E);
    for (int e = s0 + threadIdx.x; e < s1; e += HTHREADS) {
        int d = eidx[(size_t)(E + e) * st];
        atomicAdd(&hl[d >> 8], 1);
    }
    __syncthreads();
    for (int i = threadIdx.x; i < K; i += HTHREADS)
        H[(size_t)blockIdx.x * K + i] = hl[i];
}

// wave per bucket: exclusive prefix of H[c][b] over c, 64 chunks/iteration
__global__ __launch_bounds__(THREADS) void k_colscan(int* __restrict__ H,
                                                     int* __restrict__ btot,
                                                     int K, int nchunk) {
    int b = (blockIdx.x * THREADS + threadIdx.x) >> 6;  // bucket = wave id
    if (b >= K) return;                                  // whole wave exits
    int lane = threadIdx.x & 63;
    int run = 0;
    for (int i = 0; i < nchunk; i += 64) {
        int c = i + lane;
        int v = H[(size_t)c * K + b];
        int xs = v;
#pragma unroll
        for (int off = 1; off < 64; off <<= 1) {
            int t = __shfl_up(xs, off, 64);
            if (lane >= off) xs += t;
        }
        H[(size_t)c * K + b] = run + (xs - v);  // exclusive prefix
        run += __shfl(xs, 63, 64);              // add iteration total
    }
    if (lane == 0) btot[b] = run;
}

// exclusive scan of K<=2048 bucket totals, single block
__global__ __launch_bounds__(1024) void k_basescan(const int* __restrict__ btot,
                                                   int* __restrict__ base, int K) {
    __shared__ int s0[2048], s1[2048];
    int t = threadIdx.x;
    for (int i = t; i < 2048; i += 1024) s0[i] = (i < K) ? btot[i] : 0;
    __syncthreads();
    int* src = s0; int* dst = s1;
    for (int off = 1; off < 2048; off <<= 1) {
        for (int i = t; i < 2048; i += 1024)
            dst[i] = src[i] + (i >= off ? src[i - off] : 0);
        __syncthreads();
        int* tmp = src; src = dst; dst = tmp;
    }
    for (int i = t; i < 2048; i += 1024)
        if (i < K) base[i] = (i == 0) ? 0 : src[i - 1];
    if (t == 0) base[K] = src[K - 1];
}

__global__ __launch_bounds__(HTHREADS) void k_passB(const int* __restrict__ eidx,
                                                    const int* __restrict__ flag,
                                                    int E, int C, int K,
                                                    const int* __restrict__ H,
                                                    const int* __restrict__ base,
                                                    unsigned int* __restrict__ packed) {
    __shared__ int cur[KMAX];
    int st = *flag;
    for (int i = threadIdx.x; i < K; i += HTHREADS)
        cur[i] = base[i] + H[(size_t)blockIdx.x * K + i];
    __syncthreads();
    int s0 = blockIdx.x * C;
    int s1 = min(s0 + C, E);
    for (int e = s0 + threadIdx.x; e < s1; e += HTHREADS) {
        int s = eidx[(size_t)e * st];
        int d = eidx[(size_t)(E + e) * st];
        int pos = atomicAdd(&cur[d >> 8], 1);
        packed[pos] = ((unsigned)s << 8) | (unsigned)(d & 255);
    }
}

// per-bucket counting sort: packed -> csr (src by node), rowptr, dinv
__global__ __launch_bounds__(NB) void k_passC(const unsigned int* __restrict__ pk,
                                              const int* __restrict__ base,
                                              int K, int N,
                                              int* __restrict__ csr,
                                              int* __restrict__ rowptr,
                                              float* __restrict__ dinv) {
    __shared__ int cnt[NB];
    __shared__ int scn[NB];
    __shared__ int cur[NB];
    int b = blockIdx.x;
    int b0 = base[b], b1e = base[b + 1];
    int t = threadIdx.x;
    cnt[t] = 0;
    __syncthreads();
    for (int e = b0 + t; e < b1e; e += NB)
        atomicAdd(&cnt[pk[e] & 255u], 1);
    __syncthreads();
    int val = cnt[t];
    scn[t] = val;
    __syncthreads();
    for (int off = 1; off < NB; off <<= 1) {
        int tmp = (t >= off) ? scn[t - off] : 0;
        __syncthreads();
        scn[t] += tmp;
        __syncthreads();
    }
    int excl = b0 + scn[t] - val;
    cur[t] = excl;
    int v = b * NB + t;
    if (v < N) {
        rowptr[v] = excl;
        dinv[v] = rsqrtf((float)val + 1.0f);
    }
    if (b == K - 1 && t == 0) rowptr[N] = b1e;
    __syncthreads();
    for (int e = b0 + t; e < b1e; e += NB) {
        unsigned p = pk[e];
        int pos = atomicAdd(&cur[p & 255u], 1);
        csr[pos] = (int)(p >> 8);
    }
}

// reg-blocked GEMM1: 64-row tile, 4x4 per thread, xT transposed in LDS.
__global__ __launch_bounds__(THREADS) void k_gemm1(const float* __restrict__ x,
                                                   const float* __restrict__ W1,
                                                   const float* __restrict__ dinv,
                                                   __half* __restrict__ g1, int N) {
    __shared__ float xT[128 * 65];   // [k][r]
    __shared__ float Wl[128 * 64];   // [k][c]
    for (int i = threadIdx.x; i < 128 * 64; i += THREADS) Wl[i] = W1[i];
    int row0 = blockIdx.x * 64;
    int kq = threadIdx.x & 31;
    int rr = threadIdx.x >> 5;
#pragma unroll
    for (int it = 0; it < 8; ++it) {
        int r = rr + it * 8;
        int gr = row0 + r;
        float4 xv = make_float4(0.f, 0.f, 0.f, 0.f);
        if (gr < N) xv = *(const float4*)(x + (size_t)gr * 128 + kq * 4);
        xT[(4 * kq + 0) * 65 + r] = xv.x;
        xT[(4 * kq + 1) * 65 + r] = xv.y;
        xT[(4 * kq + 2) * 65 + r] = xv.z;
        xT[(4 * kq + 3) * 65 + r] = xv.w;
    }
    __syncthreads();
    int tx = threadIdx.x & 15;
    int ty = threadIdx.x >> 4;
    float acc[4][4] = {};
#pragma unroll 4
    for (int k = 0; k < 128; ++k) {
        float4 a = *(const float4*)&xT[k * 65 + ty * 4];
        float4 b = *(const float4*)&Wl[k * 64 + tx * 4];
        acc[0][0] = fmaf(a.x, b.x, acc[0][0]);
        acc[0][1] = fmaf(a.x, b.y, acc[0][1]);
        acc[0][2] = fmaf(a.x, b.z, acc[0][2]);
        acc[0][3] = fmaf(a.x, b.w, acc[0][3]);
        acc[1][0] = fmaf(a.y, b.x, acc[1][0]);
        acc[1][1] = fmaf(a.y, b.y, acc[1][1]);
        acc[1][2] = fmaf(a.y, b.z, acc[1][2]);
        acc[1][3] = fmaf(a.y, b.w, acc[1][3]);
        acc[2][0] = fmaf(a.z, b.x, acc[2][0]);
        acc[2][1] = fmaf(a.z, b.y, acc[2][1]);
        acc[2][2] = fmaf(a.z, b.z, acc[2][2]);
        acc[2][3] = fmaf(a.z, b.w, acc[2][3]);
        acc[3][0] = fmaf(a.w, b.x, acc[3][0]);
        acc[3][1] = fmaf(a.w, b.y, acc[3][1]);
        acc[3][2] = fmaf(a.w, b.z, acc[3][2]);
        acc[3][3] = fmaf(a.w, b.w, acc[3][3]);
    }
#pragma unroll
    for (int i = 0; i < 4; ++i) {
        int gr = row0 + ty * 4 + i;
        if (gr < N) {
            float dr = dinv[gr];
            Half4 o;
            o.a = __floats2half2_rn(acc[i][0] * dr, acc[i][1] * dr);
            o.b = __floats2half2_rn(acc[i][2] * dr, acc[i][3] * dr);
            *(Half4*)(g1 + (size_t)gr * 64 + tx * 4) = o;
        }
    }
}

// 32 lanes per node, lane f handles half2 feature pair f; 8-deep gather
__global__ __launch_bounds__(THREADS) void k_agg1(const int* __restrict__ rowptr,
                                                  const int* __restrict__ csr,
                                                  const __half* __restrict__ g1h,
                                                  const float* __restrict__ dinv,
                                                  const float* __restrict__ b1,
                                                  __half* __restrict__ h1h, int N) {
    const __half2* g1 = (const __half2*)g1h;
    __half2* h1 = (__half2*)h1h;
    int v = (blockIdx.x * THREADS + threadIdx.x) >> 5;
    if (v >= N) return;
    int f = threadIdx.x & 31;
    int beg = rowptr[v], end = rowptr[v + 1];
    float2 s = __half22float2(g1[(size_t)v * 32 + f]);
    float sx = s.x, sy = s.y;
    int j = beg;
    for (; j + 8 <= end; j += 8) {
        int s0 = csr[j + 0], s1 = csr[j + 1], s2 = csr[j + 2], s3 = csr[j + 3];
        int s4 = csr[j + 4], s5 = csr[j + 5], s6 = csr[j + 6], s7 = csr[j + 7];
        __half2 a0 = g1[(size_t)s0 * 32 + f];
        __half2 a1 = g1[(size_t)s1 * 32 + f];
        __half2 a2 = g1[(size_t)s2 * 32 + f];
        __half2 a3 = g1[(size_t)s3 * 32 + f];
        __half2 a4 = g1[(size_t)s4 * 32 + f];
        __half2 a5 = g1[(size_t)s5 * 32 + f];
        __half2 a6 = g1[(size_t)s6 * 32 + f];
        __half2 a7 = g1[(size_t)s7 * 32 + f];
        float2 f0 = __half22float2(a0), f1 = __half22float2(a1);
        float2 f2 = __half22float2(a2), f3 = __half22float2(a3);
        float2 f4 = __half22float2(a4), f5 = __half22float2(a5);
        float2 f6 = __half22float2(a6), f7 = __half22float2(a7);
        sx += ((f0.x + f1.x) + (f2.x + f3.x)) + ((f4.x + f5.x) + (f6.x + f7.x));
        sy += ((f0.y + f1.y) + (f2.y + f3.y)) + ((f4.y + f5.y) + (f6.y + f7.y));
    }
    for (; j < end; ++j) {
        float2 a = __half22float2(g1[(size_t)csr[j] * 32 + f]);
        sx += a.x; sy += a.y;
    }
    float dr = dinv[v];
    float h0 = fmaxf(fmaf(dr, sx, b1[2 * f + 0]), 0.0f);
    float h1v = fmaxf(fmaf(dr, sy, b1[2 * f + 1]), 0.0f);
    h1[(size_t)v * 32 + f] = __floats2half2_rn(h0, h1v);
}

// reg-blocked GEMM2: 128-row tile, 4x4 per thread, h1T (fp32) in LDS.
__global__ __launch_bounds__(THREADS) void k_gemm2(const __half* __restrict__ h1,
                                                   const float* __restrict__ W2,
                                                   const float* __restrict__ dinv,
                                                   __half* __restrict__ g2, int N) {
    __shared__ float hT[64 * 129];
    __shared__ float Wl[64 * 32];
    for (int i = threadIdx.x; i < 64 * 32; i += THREADS) Wl[i] = W2[i];
    int row0 = blockIdx.x * 128;
    int kq = threadIdx.x & 31;
    int rr = threadIdx.x >> 5;
#pragma unroll
    for (int it = 0; it < 16; ++it) {
        int r = rr + it * 8;
        int gr = row0 + r;
        __half2 v = __floats2half2_rn(0.f, 0.f);
        if (gr < N) v = ((const __half2*)(h1 + (size_t)gr * 64))[kq];
        float2 fv = __half22float2(v);
        hT[(2 * kq + 0) * 129 + r] = fv.x;
        hT[(2 * kq + 1) * 129 + r] = fv.y;
    }
    __syncthreads();
    int tx = threadIdx.x & 7;
    int ty = threadIdx.x >> 3;
    float acc[4][4] = {};
#pragma unroll 4
    for (int k = 0; k < 64; ++k) {
        float4 a = *(const float4*)&hT[k * 129 + ty * 4];
        float4 b = *(const float4*)&Wl[k * 32 + tx * 4];
        acc[0][0] = fmaf(a.x, b.x, acc[0][0]);
        acc[0][1] = fmaf(a.x, b.y, acc[0][1]);
        acc[0][2] = fmaf(a.x, b.z, acc[0][2]);
        acc[0][3] = fmaf(a.x, b.w, acc[0][3]);
        acc[1][0] = fmaf(a.y, b.x, acc[1][0]);
        acc[1][1] = fmaf(a.y, b.y, acc[1][1]);
        acc[1][2] = fmaf(a.y, b.z, acc[1][2]);
        acc[1][3] = fmaf(a.y, b.w, acc[1][3]);
        acc[2][0] = fmaf(a.z, b.x, acc[2][0]);
        acc[2][1] = fmaf(a.z, b.y, acc[2][1]);
        acc[2][2] = fmaf(a.z, b.z, acc[2][2]);
        acc[2][3] = fmaf(a.z, b.w, acc[2][3]);
        acc[3][0] = fmaf(a.w, b.x, acc[3][0]);
        acc[3][1] = fmaf(a.w, b.y, acc[3][1]);
        acc[3][2] = fmaf(a.w, b.z, acc[3][2]);
        acc[3][3] = fmaf(a.w, b.w, acc[3][3]);
    }
#pragma unroll
    for (int i = 0; i < 4; ++i) {
        int gr = row0 + ty * 4 + i;
        if (gr < N) {
            float dr = dinv[gr];
            Half4 o;
            o.a = __floats2half2_rn(acc[i][0] * dr, acc[i][1] * dr);
            o.b = __floats2half2_rn(acc[i][2] * dr, acc[i][3] * dr);
            *(Half4*)(g2 + (size_t)gr * 32 + tx * 4) = o;
        }
    }
}

// 16 lanes per node, lane f handles half2 feature pair f; 8-deep gather
__global__ __launch_bounds__(THREADS) void k_agg2(const int* __restrict__ rowptr,
                                                  const int* __restrict__ csr,
                                                  const __half* __restrict__ g2h,
                                                  const float* __restrict__ dinv,
                                                  const float* __restrict__ b2,
                                                  float* __restrict__ out, int N) {
    const __half2* g2 = (const __half2*)g2h;
    int v = (blockIdx.x * THREADS + threadIdx.x) >> 4;
    if (v >= N) return;
    int f = threadIdx.x & 15;
    int beg = rowptr[v], end = rowptr[v + 1];
    float2 s = __half22float2(g2[(size_t)v * 16 + f]);
    float sx = s.x, sy = s.y;
    int j = beg;
    for (; j + 8 <= end; j += 8) {
        int s0 = csr[j + 0], s1 = csr[j + 1], s2 = csr[j + 2], s3 = csr[j + 3];
        int s4 = csr[j + 4], s5 = csr[j + 5], s6 = csr[j + 6], s7 = csr[j + 7];
        __half2 a0 = g2[(size_t)s0 * 16 + f];
        __half2 a1 = g2[(size_t)s1 * 16 + f];
        __half2 a2 = g2[(size_t)s2 * 16 + f];
        __half2 a3 = g2[(size_t)s3 * 16 + f];
        __half2 a4 = g2[(size_t)s4 * 16 + f];
        __half2 a5 = g2[(size_t)s5 * 16 + f];
        __half2 a6 = g2[(size_t)s6 * 16 + f];
        __half2 a7 = g2[(size_t)s7 * 16 + f];
        float2 f0 = __half22float2(a0), f1 = __half22float2(a1);
        float2 f2 = __half22float2(a2), f3 = __half22float2(a3);
        float2 f4 = __half22float2(a4), f5 = __half22float2(a5);
        float2 f6 = __half22float2(a6), f7 = __half22float2(a7);
        sx += ((f0.x + f1.x) + (f2.x + f3.x)) + ((f4.x + f5.x) + (f6.x + f7.x));
        sy += ((f0.y + f1.y) + (f2.y + f3.y)) + ((f4.y + f5.y) + (f6.y + f7.y));
    }
    for (; j < end; ++j) {
        float2 a = __half22float2(g2[(size_t)csr[j] * 16 + f]);
        sx += a.x; sy += a.y;
    }
    float dr = dinv[v];
    float2 o;
    o.x = fmaf(dr, sx, b2[2 * f + 0]);
    o.y = fmaf(dr, sy, b2[2 * f + 1]);
    ((float2*)out)[(size_t)v * 16 + f] = o;
}

extern "C" void kernel_launch(void* const* d_in, const int* in_sizes, int n_in,
                              void* d_out, int out_size, void* d_ws, size_t ws_size,
                              hipStream_t stream) {
    const float* x  = (const float*)d_in[0];
    const int* eidx = (const int*)d_in[1];
    const float* W1 = (const float*)d_in[2];
    const float* b1 = (const float*)d_in[3];
    const float* W2 = (const float*)d_in[4];
    const float* b2 = (const float*)d_in[5];
    float* out = (float*)d_out;

    const int N = in_sizes[0] / 128;   // 100000
    const int E = in_sizes[1] / 2;     // 3200000
    const int K = (N + NB - 1) / NB;   // 391
    const int C = (E + NCHUNK - 1) / NCHUNK;

    // ws layout (ints), no aliasing; total ~61 MB
    int* flag   = (int*)d_ws;                            // 64
    int* H      = flag + 64;                             // NCHUNK*400
    int* btot   = H + (size_t)NCHUNK * 400;              // 400
    int* base   = btot + 400;                            // 448
    unsigned int* packed = (unsigned int*)(base + 448);  // E
    int* csr    = (int*)(packed + E);                    // E
    int* rowptr = csr + E;                               // N+1 (100032)
    float* dinv = (float*)(rowptr + 100032);             // 100032
    __half* g1  = (__half*)(dinv + 100032);              // N*64 halfs
    __half* h1  = g1 + (size_t)N * 64;                   // N*64 halfs
    __half* g2  = h1 + (size_t)N * 64;                   // N*32 halfs

    k_detect<<<1, 64, 0, stream>>>(eidx, flag);
    k_hist<<<NCHUNK, HTHREADS, 0, stream>>>(eidx, flag, E, C, K, H);
    k_colscan<<<(K * 64 + THREADS - 1) / THREADS, THREADS, 0, stream>>>(H, btot, K, NCHUNK);
    k_basescan<<<1, 1024, 0, stream>>>(btot, base, K);
    k_passB<<<NCHUNK, HTHREADS, 0, stream>>>(eidx, flag, E, C, K, H, base, packed);
    k_passC<<<K, NB, 0, stream>>>(packed, base, K, N, csr, rowptr, dinv);
    k_gemm1<<<(N + 63) / 64, THREADS, 0, stream>>>(x, W1, dinv, g1, N);
    k_agg1<<<(N * 32 + THREADS - 1) / THREADS, THREADS, 0, stream>>>(rowptr, csr, g1, dinv, b1, h1, N);
    k_gemm2<<<(N + 127) / 128, THREADS, 0, stream>>>(h1, W2, dinv, g2, N);
    k_agg2<<<(N * 16 + THREADS - 1) / THREADS, THREADS, 0, stream>>>(rowptr, csr, g2, dinv, b2, out, N);
}

// Round 10
// 274.041 us; speedup vs baseline: 1.8233x; 1.0088x over previous
//
#include <hip/hip_runtime.h>
#include <hip/hip_fp16.h>

#define THREADS 256
#define HTHREADS 512
#define NB 256           // nodes per bucket
#define KMAX 400         // >= ceil(N/NB)=391
#define NCHUNK 1024      // edge chunks for bucket sort (4 blocks/CU)

struct alignas(8) Half4 { __half2 a, b; };

// ---------------------------------------------------------------------------
// detect -> hist(LDS bucket histogram) -> colscan (wave/bucket shfl scan) ->
// basescan -> passB (packed bucket-sorted edges) -> passC (per-bucket
// counting sort -> node CSR + rowptr + dinv) -> gemm1 (reg-blocked 4x4) ->
// agg1 (32-lane/node, 16-deep half2 gather) -> gemm2 (reg-blocked 4x4) ->
// agg2 (16-lane/node, 16-deep, out fp32)
//
// R9 lesson: agg gathers are request-rate/latency-bound (3.4 TB/s, VGPR=20
// shows compiler serialized the 8-deep batch). This round: 16-deep ILP.
// packed edge = (src << 8) | (dst & 255); bucket = dst >> 8
// ---------------------------------------------------------------------------

__global__ void k_detect(const int* __restrict__ e32, int* __restrict__ flag) {
    if (blockIdx.x == 0 && threadIdx.x == 0) {
        int st = 2;
        for (int i = 0; i < 64; ++i)
            if (e32[2 * i + 1] != 0) { st = 1; break; }
        *flag = st;
    }
}

__global__ __launch_bounds__(HTHREADS) void k_hist(const int* __restrict__ eidx,
                                                   const int* __restrict__ flag,
                                                   int E, int C, int K,
                                                   int* __restrict__ H) {
    __shared__ int hl[KMAX];
    int st = *flag;
    for (int i = threadIdx.x; i < K; i += HTHREADS) hl[i] = 0;
    __syncthreads();
    int s0 = blockIdx.x * C;
    int s1 = min(s0 + C, E);
    for (int e = s0 + threadIdx.x; e < s1; e += HTHREADS) {
        int d = eidx[(size_t)(E + e) * st];
        atomicAdd(&hl[d >> 8], 1);
    }
    __syncthreads();
    for (int i = threadIdx.x; i < K; i += HTHREADS)
        H[(size_t)blockIdx.x * K + i] = hl[i];
}

// wave per bucket: exclusive prefix of H[c][b] over c, 64 chunks/iteration
__global__ __launch_bounds__(THREADS) void k_colscan(int* __restrict__ H,
                                                     int* __restrict__ btot,
                                                     int K, int nchunk) {
    int b = (blockIdx.x * THREADS + threadIdx.x) >> 6;
    if (b >= K) return;
    int lane = threadIdx.x & 63;
    int run = 0;
    for (int i = 0; i < nchunk; i += 64) {
        int c = i + lane;
        int v = H[(size_t)c * K + b];
        int xs = v;
#pragma unroll
        for (int off = 1; off < 64; off <<= 1) {
            int t = __shfl_up(xs, off, 64);
            if (lane >= off) xs += t;
        }
        H[(size_t)c * K + b] = run + (xs - v);
        run += __shfl(xs, 63, 64);
    }
    if (lane == 0) btot[b] = run;
}

// exclusive scan of K<=2048 bucket totals, single block
__global__ __launch_bounds__(1024) void k_basescan(const int* __restrict__ btot,
                                                   int* __restrict__ base, int K) {
    __shared__ int s0[2048], s1[2048];
    int t = threadIdx.x;
    for (int i = t; i < 2048; i += 1024) s0[i] = (i < K) ? btot[i] : 0;
    __syncthreads();
    int* src = s0; int* dst = s1;
    for (int off = 1; off < 2048; off <<= 1) {
        for (int i = t; i < 2048; i += 1024)
            dst[i] = src[i] + (i >= off ? src[i - off] : 0);
        __syncthreads();
        int* tmp = src; src = dst; dst = tmp;
    }
    for (int i = t; i < 2048; i += 1024)
        if (i < K) base[i] = (i == 0) ? 0 : src[i - 1];
    if (t == 0) base[K] = src[K - 1];
}

__global__ __launch_bounds__(HTHREADS) void k_passB(const int* __restrict__ eidx,
                                                    const int* __restrict__ flag,
                                                    int E, int C, int K,
                                                    const int* __restrict__ H,
                                                    const int* __restrict__ base,
                                                    unsigned int* __restrict__ packed) {
    __shared__ int cur[KMAX];
    int st = *flag;
    for (int i = threadIdx.x; i < K; i += HTHREADS)
        cur[i] = base[i] + H[(size_t)blockIdx.x * K + i];
    __syncthreads();
    int s0 = blockIdx.x * C;
    int s1 = min(s0 + C, E);
    for (int e = s0 + threadIdx.x; e < s1; e += HTHREADS) {
        int s = eidx[(size_t)e * st];
        int d = eidx[(size_t)(E + e) * st];
        int pos = atomicAdd(&cur[d >> 8], 1);
        packed[pos] = ((unsigned)s << 8) | (unsigned)(d & 255);
    }
}

// per-bucket counting sort: packed -> csr (src by node), rowptr, dinv
__global__ __launch_bounds__(NB) void k_passC(const unsigned int* __restrict__ pk,
                                              const int* __restrict__ base,
                                              int K, int N,
                                              int* __restrict__ csr,
                                              int* __restrict__ rowptr,
                                              float* __restrict__ dinv) {
    __shared__ int cnt[NB];
    __shared__ int scn[NB];
    __shared__ int cur[NB];
    int b = blockIdx.x;
    int b0 = base[b], b1e = base[b + 1];
    int t = threadIdx.x;
    cnt[t] = 0;
    __syncthreads();
    for (int e = b0 + t; e < b1e; e += NB)
        atomicAdd(&cnt[pk[e] & 255u], 1);
    __syncthreads();
    int val = cnt[t];
    scn[t] = val;
    __syncthreads();
    for (int off = 1; off < NB; off <<= 1) {
        int tmp = (t >= off) ? scn[t - off] : 0;
        __syncthreads();
        scn[t] += tmp;
        __syncthreads();
    }
    int excl = b0 + scn[t] - val;
    cur[t] = excl;
    int v = b * NB + t;
    if (v < N) {
        rowptr[v] = excl;
        dinv[v] = rsqrtf((float)val + 1.0f);
    }
    if (b == K - 1 && t == 0) rowptr[N] = b1e;
    __syncthreads();
    for (int e = b0 + t; e < b1e; e += NB) {
        unsigned p = pk[e];
        int pos = atomicAdd(&cur[p & 255u], 1);
        csr[pos] = (int)(p >> 8);
    }
}

// reg-blocked GEMM1: 64-row tile, 4x4 per thread, xT transposed in LDS.
__global__ __launch_bounds__(THREADS) void k_gemm1(const float* __restrict__ x,
                                                   const float* __restrict__ W1,
                                                   const float* __restrict__ dinv,
                                                   __half* __restrict__ g1, int N) {
    __shared__ float xT[128 * 65];
    __shared__ float Wl[128 * 64];
    for (int i = threadIdx.x; i < 128 * 64; i += THREADS) Wl[i] = W1[i];
    int row0 = blockIdx.x * 64;
    int kq = threadIdx.x & 31;
    int rr = threadIdx.x >> 5;
#pragma unroll
    for (int it = 0; it < 8; ++it) {
        int r = rr + it * 8;
        int gr = row0 + r;
        float4 xv = make_float4(0.f, 0.f, 0.f, 0.f);
        if (gr < N) xv = *(const float4*)(x + (size_t)gr * 128 + kq * 4);
        xT[(4 * kq + 0) * 65 + r] = xv.x;
        xT[(4 * kq + 1) * 65 + r] = xv.y;
        xT[(4 * kq + 2) * 65 + r] = xv.z;
        xT[(4 * kq + 3) * 65 + r] = xv.w;
    }
    __syncthreads();
    int tx = threadIdx.x & 15;
    int ty = threadIdx.x >> 4;
    float acc[4][4] = {};
#pragma unroll 4
    for (int k = 0; k < 128; ++k) {
        float4 a = *(const float4*)&xT[k * 65 + ty * 4];
        float4 b = *(const float4*)&Wl[k * 64 + tx * 4];
        acc[0][0] = fmaf(a.x, b.x, acc[0][0]);
        acc[0][1] = fmaf(a.x, b.y, acc[0][1]);
        acc[0][2] = fmaf(a.x, b.z, acc[0][2]);
        acc[0][3] = fmaf(a.x, b.w, acc[0][3]);
        acc[1][0] = fmaf(a.y, b.x, acc[1][0]);
        acc[1][1] = fmaf(a.y, b.y, acc[1][1]);
        acc[1][2] = fmaf(a.y, b.z, acc[1][2]);
        acc[1][3] = fmaf(a.y, b.w, acc[1][3]);
        acc[2][0] = fmaf(a.z, b.x, acc[2][0]);
        acc[2][1] = fmaf(a.z, b.y, acc[2][1]);
        acc[2][2] = fmaf(a.z, b.z, acc[2][2]);
        acc[2][3] = fmaf(a.z, b.w, acc[2][3]);
        acc[3][0] = fmaf(a.w, b.x, acc[3][0]);
        acc[3][1] = fmaf(a.w, b.y, acc[3][1]);
        acc[3][2] = fmaf(a.w, b.z, acc[3][2]);
        acc[3][3] = fmaf(a.w, b.w, acc[3][3]);
    }
#pragma unroll
    for (int i = 0; i < 4; ++i) {
        int gr = row0 + ty * 4 + i;
        if (gr < N) {
            float dr = dinv[gr];
            Half4 o;
            o.a = __floats2half2_rn(acc[i][0] * dr, acc[i][1] * dr);
            o.b = __floats2half2_rn(acc[i][2] * dr, acc[i][3] * dr);
            *(Half4*)(g1 + (size_t)gr * 64 + tx * 4) = o;
        }
    }
}

// 32 lanes per node, lane f = half2 feature pair; 16-deep gather pipeline
__global__ __launch_bounds__(THREADS) void k_agg1(const int* __restrict__ rowptr,
                                                  const int* __restrict__ csr,
                                                  const __half* __restrict__ g1h,
                                                  const float* __restrict__ dinv,
                                                  const float* __restrict__ b1,
                                                  __half* __restrict__ h1h, int N) {
    const __half2* g1 = (const __half2*)g1h;
    __half2* h1 = (__half2*)h1h;
    int v = (blockIdx.x * THREADS + threadIdx.x) >> 5;
    if (v >= N) return;
    int f = threadIdx.x & 31;
    int beg = rowptr[v], end = rowptr[v + 1];
    float2 s = __half22float2(g1[(size_t)v * 32 + f]);
    float sx = s.x, sy = s.y;
    int j = beg;
    for (; j + 16 <= end; j += 16) {
        int idx[16];
#pragma unroll
        for (int u = 0; u < 16; ++u) idx[u] = csr[j + u];
        __half2 a[16];
#pragma unroll
        for (int u = 0; u < 16; ++u) a[u] = g1[(size_t)idx[u] * 32 + f];
        float tx = 0.f, ty = 0.f;
#pragma unroll
        for (int u = 0; u < 16; ++u) {
            float2 fa = __half22float2(a[u]);
            tx += fa.x; ty += fa.y;
        }
        sx += tx; sy += ty;
    }
    if (j + 8 <= end) {
        int idx[8];
#pragma unroll
        for (int u = 0; u < 8; ++u) idx[u] = csr[j + u];
        __half2 a[8];
#pragma unroll
        for (int u = 0; u < 8; ++u) a[u] = g1[(size_t)idx[u] * 32 + f];
#pragma unroll
        for (int u = 0; u < 8; ++u) {
            float2 fa = __half22float2(a[u]);
            sx += fa.x; sy += fa.y;
        }
        j += 8;
    }
    for (; j < end; ++j) {
        float2 a = __half22float2(g1[(size_t)csr[j] * 32 + f]);
        sx += a.x; sy += a.y;
    }
    float dr = dinv[v];
    float h0 = fmaxf(fmaf(dr, sx, b1[2 * f + 0]), 0.0f);
    float h1v = fmaxf(fmaf(dr, sy, b1[2 * f + 1]), 0.0f);
    h1[(size_t)v * 32 + f] = __floats2half2_rn(h0, h1v);
}

// reg-blocked GEMM2: 128-row tile, 4x4 per thread, h1T (fp32) in LDS.
__global__ __launch_bounds__(THREADS) void k_gemm2(const __half* __restrict__ h1,
                                                   const float* __restrict__ W2,
                                                   const float* __restrict__ dinv,
                                                   __half* __restrict__ g2, int N) {
    __shared__ float hT[64 * 129];
    __shared__ float Wl[64 * 32];
    for (int i = threadIdx.x; i < 64 * 32; i += THREADS) Wl[i] = W2[i];
    int row0 = blockIdx.x * 128;
    int kq = threadIdx.x & 31;
    int rr = threadIdx.x >> 5;
#pragma unroll
    for (int it = 0; it < 16; ++it) {
        int r = rr + it * 8;
        int gr = row0 + r;
        __half2 v = __floats2half2_rn(0.f, 0.f);
        if (gr < N) v = ((const __half2*)(h1 + (size_t)gr * 64))[kq];
        float2 fv = __half22float2(v);
        hT[(2 * kq + 0) * 129 + r] = fv.x;
        hT[(2 * kq + 1) * 129 + r] = fv.y;
    }
    __syncthreads();
    int tx = threadIdx.x & 7;
    int ty = threadIdx.x >> 3;
    float acc[4][4] = {};
#pragma unroll 4
    for (int k = 0; k < 64; ++k) {
        float4 a = *(const float4*)&hT[k * 129 + ty * 4];
        float4 b = *(const float4*)&Wl[k * 32 + tx * 4];
        acc[0][0] = fmaf(a.x, b.x, acc[0][0]);
        acc[0][1] = fmaf(a.x, b.y, acc[0][1]);
        acc[0][2] = fmaf(a.x, b.z, acc[0][2]);
        acc[0][3] = fmaf(a.x, b.w, acc[0][3]);
        acc[1][0] = fmaf(a.y, b.x, acc[1][0]);
        acc[1][1] = fmaf(a.y, b.y, acc[1][1]);
        acc[1][2] = fmaf(a.y, b.z, acc[1][2]);
        acc[1][3] = fmaf(a.y, b.w, acc[1][3]);
        acc[2][0] = fmaf(a.z, b.x, acc[2][0]);
        acc[2][1] = fmaf(a.z, b.y, acc[2][1]);
        acc[2][2] = fmaf(a.z, b.z, acc[2][2]);
        acc[2][3] = fmaf(a.z, b.w, acc[2][3]);
        acc[3][0] = fmaf(a.w, b.x, acc[3][0]);
        acc[3][1] = fmaf(a.w, b.y, acc[3][1]);
        acc[3][2] = fmaf(a.w, b.z, acc[3][2]);
        acc[3][3] = fmaf(a.w, b.w, acc[3][3]);
    }
#pragma unroll
    for (int i = 0; i < 4; ++i) {
        int gr = row0 + ty * 4 + i;
        if (gr < N) {
            float dr = dinv[gr];
            Half4 o;
            o.a = __floats2half2_rn(acc[i][0] * dr, acc[i][1] * dr);
            o.b = __floats2half2_rn(acc[i][2] * dr, acc[i][3] * dr);
            *(Half4*)(g2 + (size_t)gr * 32 + tx * 4) = o;
        }
    }
}

// 16 lanes per node, lane f = half2 feature pair; 16-deep gather pipeline
__global__ __launch_bounds__(THREADS) void k_agg2(const int* __restrict__ rowptr,
                                                  const int* __restrict__ csr,
                                                  const __half* __restrict__ g2h,
                                                  const float* __restrict__ dinv,
                                                  const float* __restrict__ b2,
                                                  float* __restrict__ out, int N) {
    const __half2* g2 = (const __half2*)g2h;
    int v = (blockIdx.x * THREADS + threadIdx.x) >> 4;
    if (v >= N) return;
    int f = threadIdx.x & 15;
    int beg = rowptr[v], end = rowptr[v + 1];
    float2 s = __half22float2(g2[(size_t)v * 16 + f]);
    float sx = s.x, sy = s.y;
    int j = beg;
    for (; j + 16 <= end; j += 16) {
        int idx[16];
#pragma unroll
        for (int u = 0; u < 16; ++u) idx[u] = csr[j + u];
        __half2 a[16];
#pragma unroll
        for (int u = 0; u < 16; ++u) a[u] = g2[(size_t)idx[u] * 16 + f];
        float tx = 0.f, ty = 0.f;
#pragma unroll
        for (int u = 0; u < 16; ++u) {
            float2 fa = __half22float2(a[u]);
            tx += fa.x; ty += fa.y;
        }
        sx += tx; sy += ty;
    }
    if (j + 8 <= end) {
        int idx[8];
#pragma unroll
        for (int u = 0; u < 8; ++u) idx[u] = csr[j + u];
        __half2 a[8];
#pragma unroll
        for (int u = 0; u < 8; ++u) a[u] = g2[(size_t)idx[u] * 16 + f];
#pragma unroll
        for (int u = 0; u < 8; ++u) {
            float2 fa = __half22float2(a[u]);
            sx += fa.x; sy += fa.y;
        }
        j += 8;
    }
    for (; j < end; ++j) {
        float2 a = __half22float2(g2[(size_t)csr[j] * 16 + f]);
        sx += a.x; sy += a.y;
    }
    float dr = dinv[v];
    float2 o;
    o.x = fmaf(dr, sx, b2[2 * f + 0]);
    o.y = fmaf(dr, sy, b2[2 * f + 1]);
    ((float2*)out)[(size_t)v * 16 + f] = o;
}

extern "C" void kernel_launch(void* const* d_in, const int* in_sizes, int n_in,
                              void* d_out, int out_size, void* d_ws, size_t ws_size,
                              hipStream_t stream) {
    const float* x  = (const float*)d_in[0];
    const int* eidx = (const int*)d_in[1];
    const float* W1 = (const float*)d_in[2];
    const float* b1 = (const float*)d_in[3];
    const float* W2 = (const float*)d_in[4];
    const float* b2 = (const float*)d_in[5];
    float* out = (float*)d_out;

    const int N = in_sizes[0] / 128;   // 100000
    const int E = in_sizes[1] / 2;     // 3200000
    const int K = (N + NB - 1) / NB;   // 391
    const int C = (E + NCHUNK - 1) / NCHUNK;

    // ws layout (ints), no aliasing; total ~61 MB
    int* flag   = (int*)d_ws;                            // 64
    int* H      = flag + 64;                             // NCHUNK*400
    int* btot   = H + (size_t)NCHUNK * 400;              // 400
    int* base   = btot + 400;                            // 448
    unsigned int* packed = (unsigned int*)(base + 448);  // E
    int* csr    = (int*)(packed + E);                    // E
    int* rowptr = csr + E;                               // N+1 (100032)
    float* dinv = (float*)(rowptr + 100032);             // 100032
    __half* g1  = (__half*)(dinv + 100032);              // N*64 halfs
    __half* h1  = g1 + (size_t)N * 64;                   // N*64 halfs
    __half* g2  = h1 + (size_t)N * 64;                   // N*32 halfs

    k_detect<<<1, 64, 0, stream>>>(eidx, flag);
    k_hist<<<NCHUNK, HTHREADS, 0, stream>>>(eidx, flag, E, C, K, H);
    k_colscan<<<(K * 64 + THREADS - 1) / THREADS, THREADS, 0, stream>>>(H, btot, K, NCHUNK);
    k_basescan<<<1, 1024, 0, stream>>>(btot, base, K);
    k_passB<<<NCHUNK, HTHREADS, 0, stream>>>(eidx, flag, E, C, K, H, base, packed);
    k_passC<<<K, NB, 0, stream>>>(packed, base, K, N, csr, rowptr, dinv);
    k_gemm1<<<(N + 63) / 64, THREADS, 0, stream>>>(x, W1, dinv, g1, N);
    k_agg1<<<(N * 32 + THREADS - 1) / THREADS, THREADS, 0, stream>>>(rowptr, csr, g1, dinv, b1, h1, N);
    k_gemm2<<<(N + 127) / 128, THREADS, 0, stream>>>(h1, W2, dinv, g2, N);
    k_agg2<<<(N * 16 + THREADS - 1) / THREADS, THREADS, 0, stream>>>(rowptr, csr, g2, dinv, b2, out, N);
}